// Round 17
// baseline (110.763 us; speedup 1.0000x reference)
//
#include <hip/hip_runtime.h>

typedef __bf16 bf16_t;
typedef __bf16 bf16x8 __attribute__((ext_vector_type(8)));
typedef __bf16 bf16x4 __attribute__((ext_vector_type(4)));
typedef float f32x4 __attribute__((ext_vector_type(4)));
typedef float f32x16 __attribute__((ext_vector_type(16)));
typedef long longx2 __attribute__((ext_vector_type(2)));
typedef unsigned uintx2 __attribute__((ext_vector_type(2)));

static constexpr int kC = 256;   // channels
static constexpr int kN = 1024;  // tokens (32x32)
static constexpr int kB = 32;    // batch

__device__ __forceinline__ void gload_lds16(const void* g, void* l) {
  __builtin_amdgcn_global_load_lds(
      (const __attribute__((address_space(1))) unsigned int*)g,
      (__attribute__((address_space(3))) unsigned int*)l, 16, 0, 0);
}

// pack 4 f32 -> 4 fp8 e4m3 bytes (lo word then hi word)
__device__ __forceinline__ unsigned pk_fp8x4(float a, float b, float c, float d) {
  unsigned r;
  asm("v_cvt_pk_fp8_f32 %0, %1, %2" : "=v"(r) : "v"(a), "v"(b));
  asm("v_cvt_pk_fp8_f32 %0, %1, %2 op_sel:[0,0,1]" : "+v"(r) : "v"(c), "v"(d));
  return r;
}

// exchange: a's high 32 lanes <-> b's low 32 lanes (both regs updated)
__device__ __forceinline__ void pl32swap(unsigned& a, unsigned& b) {
  asm("v_permlane32_swap_b32 %0, %1" : "+v"(a), "+v"(b));
}

__device__ __forceinline__ float cross_half_sum(float rs) {
  unsigned a = __builtin_bit_cast(unsigned, rs), b = a;
  pl32swap(a, b);
  return __builtin_bit_cast(float, a) + __builtin_bit_cast(float, b);
}

// ------- fused GroupNorm (+ weight cast blocks): grid = 1024 gn + 256 castw -------
__global__ __launch_bounds__(256) void gn_castw_k(const float* __restrict__ x,
                                                  const float* __restrict__ gamma,
                                                  const float* __restrict__ beta,
                                                  bf16_t* __restrict__ hn,
                                                  const float* __restrict__ wq,
                                                  const float* __restrict__ wk,
                                                  const float* __restrict__ wv,
                                                  const float* __restrict__ wh,
                                                  bf16_t* __restrict__ wb) {
  __shared__ float xs[8 * 1040];  // [c_local][n] pad 1040
  __shared__ float red[8];
  __shared__ float stat[2];
  int t = threadIdx.x;
  if (blockIdx.x >= 1024) {  // weight cast: 256 blocks x 256 thr
    int i = (blockIdx.x - 1024) * 256 + t;
    wb[i] = (bf16_t)wq[i];
    wb[i + 65536] = (bf16_t)wk[i];
    wb[i + 131072] = (bf16_t)wv[i];
    wb[i + 196608] = (bf16_t)wh[i];
    return;
  }
  int bg = blockIdx.x;
  int b = bg >> 5, g = bg & 31;
  const float* base = x + (size_t)bg * 8192;
  float s = 0.f, q = 0.f;
#pragma unroll
  for (int i = 0; i < 8; ++i) {
    float4 v = *(const float4*)(base + i * 1024 + t * 4);
    *(float4*)(xs + i * 1040 + t * 4) = v;
    s += v.x + v.y + v.z + v.w;
    q += v.x * v.x + v.y * v.y + v.z * v.z + v.w * v.w;
  }
#pragma unroll
  for (int o = 32; o; o >>= 1) { s += __shfl_down(s, o); q += __shfl_down(q, o); }
  int w = t >> 6;
  if ((t & 63) == 0) { red[w] = s; red[4 + w] = q; }
  __syncthreads();
  if (t == 0) {
    float S = red[0] + red[1] + red[2] + red[3];
    float Q = red[4] + red[5] + red[6] + red[7];
    float mean = S * (1.f / 8192.f);
    float var = Q * (1.f / 8192.f) - mean * mean;  // biased var matches jnp.var
    stat[0] = mean;
    stat[1] = rsqrtf(var + 1e-5f);
  }
  __syncthreads();
  float mean = stat[0], rstd = stat[1];
  float gmb[8], btb[8];
#pragma unroll
  for (int j = 0; j < 8; ++j) { gmb[j] = gamma[g * 8 + j]; btb[j] = beta[g * 8 + j]; }
  bf16_t* hb = hn + (size_t)b * (kN * kC) + g * 8;
#pragma unroll
  for (int i = 0; i < 4; ++i) {
    int n = i * 256 + t;
    bf16x8 o;
#pragma unroll
    for (int j = 0; j < 8; ++j)
      o[j] = (bf16_t)((xs[j * 1040 + n] - mean) * rstd * gmb[j] + btb[j]);
    *(bf16x8*)(hb + (size_t)n * kC) = o;
  }
}

// ---- fused flash attention (R16 winner, unchanged): non-redundant QK, fp8 P/V ----
__global__ __launch_bounds__(256, 2) void fattn_k(const char* __restrict__ QT,
                                                  const char* __restrict__ KT,
                                                  const char* __restrict__ VV,
                                                  bf16_t* __restrict__ OT) {
  __shared__ char smem[70656];  // K[2][16K] | V[2][16K]@32768 | P 4K@65536 | ex 1K@69632
  char* lKc = smem;
  char* lVc = smem + 32768;
  char* pb = smem + 65536;
  float* exls = (float*)(smem + 69632);
  int t = threadIdx.x;
  int wid = t >> 6, lane = t & 63;
  int l31 = lane & 31, hi = lane >> 5;
  int qg = wid & 1, h = wid >> 1;
  int bid = blockIdx.x;
  int b = ((bid & 7) << 2) | ((bid >> 3) & 3);  // XCD swizzle
  int qt = bid >> 5;
  const char* Qb = QT + (size_t)b * (kN * kC);
  int q0 = qt * 64 + qg * 32;
  constexpr float kSc = 0.0625f * 1.44269504f;  // (1/sqrt C) * log2(e)

  long qf[16];
#pragma unroll
  for (int jj = 0; jj < 8; ++jj) {
    longx2 qp = *(const longx2*)(Qb + (size_t)(q0 + l31) * kC + hi * 128 + jj * 16);
    qf[2 * jj] = qp[0];
    qf[2 * jj + 1] = qp[1];
  }

  unsigned koff2[8];
#pragma unroll
  for (int jj = 0; jj < 8; ++jj)
    koff2[jj] = (h * 32 + l31) * 256 + (((hi * 8 + jj) ^ (l31 & 15)) << 4);
  unsigned voff2[8];
#pragma unroll
  for (int sp = 0; sp < 2; ++sp)
#pragma unroll
    for (int ct = 0; ct < 4; ++ct) {
      int c = h * 128 + ct * 32 + l31;
      voff2[sp * 4 + ct] = c * 64 + ((sp ^ ((c >> 1) & 1)) << 5) + hi * 16;
    }

  unsigned koffg[4], voffg[4];
#pragma unroll
  for (int i = 0; i < 4; ++i) {
    int ck = i * 256 + t;
    int row = ck >> 4, s = ck & 15;
    koffg[i] = row * 256 + ((s ^ (row & 15)) << 4);
    int cv = i * 256 + t;
    voffg[i] = (cv >> 2) * 1024 + ((cv & 3) << 4);
  }
  const char* kSrc = KT + (size_t)b * (kN * kC);
  const char* vSrc = VV + (size_t)b * (kC * kN);
  char* kd0 = lKc + t * 16;
  char* vd0 = lVc + t * 16;

  f32x16 acc[4] = {};
  float lsum = 0.f;

  auto STAGE = [&](int buf) {
#pragma unroll
    for (int i = 0; i < 4; ++i)
      gload_lds16(kSrc + koffg[i], kd0 + buf * 16384 + i * 4096);
#pragma unroll
    for (int i = 0; i < 4; ++i)
      gload_lds16(vSrc + voffg[i], vd0 + buf * 16384 + i * 4096);
    kSrc += 16384;
    vSrc += 64;
  };

  STAGE(0);
  for (int kt = 0; kt < 16; ++kt) {
    if (kt < 15) {
      STAGE((kt + 1) & 1);
      asm volatile("s_waitcnt vmcnt(8)" ::: "memory");
    } else {
      asm volatile("s_waitcnt vmcnt(0)" ::: "memory");
    }
    __builtin_amdgcn_s_barrier();  // A: tile staged; prev P fully consumed
    const char* bK = lKc + (kt & 1) * 16384;
    const char* bV = lVc + (kt & 1) * 16384;
    f32x16 sa = {};
    __builtin_amdgcn_s_setprio(1);
#pragma unroll
    for (int jj = 0; jj < 8; ++jj) {
      longx2 ka = *(const longx2*)(bK + koff2[jj]);
      sa = __builtin_amdgcn_mfma_f32_32x32x16_fp8_fp8(ka[0], qf[2 * jj], sa, 0, 0, 0);
      sa = __builtin_amdgcn_mfma_f32_32x32x16_fp8_fp8(ka[1], qf[2 * jj + 1], sa, 0, 0, 0);
    }
    __builtin_amdgcn_s_setprio(0);
    float rs = 0.f;
    float e0 = exp2f(sa[0] * kSc), e1 = exp2f(sa[1] * kSc);
    float e2 = exp2f(sa[2] * kSc), e3 = exp2f(sa[3] * kSc);
    float e4 = exp2f(sa[4] * kSc), e5 = exp2f(sa[5] * kSc);
    float e6 = exp2f(sa[6] * kSc), e7 = exp2f(sa[7] * kSc);
    rs += e0 + e1 + e2 + e3 + e4 + e5 + e6 + e7;
    unsigned G0 = pk_fp8x4(e0, e1, e2, e3), G1 = pk_fp8x4(e4, e5, e6, e7);
    pl32swap(G0, G1);
    e0 = exp2f(sa[8] * kSc);  e1 = exp2f(sa[9] * kSc);
    e2 = exp2f(sa[10] * kSc); e3 = exp2f(sa[11] * kSc);
    e4 = exp2f(sa[12] * kSc); e5 = exp2f(sa[13] * kSc);
    e6 = exp2f(sa[14] * kSc); e7 = exp2f(sa[15] * kSc);
    rs += e0 + e1 + e2 + e3 + e4 + e5 + e6 + e7;
    lsum += rs;
    unsigned G2 = pk_fp8x4(e0, e1, e2, e3), G3 = pk_fp8x4(e4, e5, e6, e7);
    pl32swap(G2, G3);
    *(uint4*)(pb + wid * 1024 + lane * 16) = make_uint4(G0, G1, G2, G3);
    asm volatile("s_waitcnt lgkmcnt(0)" ::: "memory");
    __builtin_amdgcn_s_barrier();  // B: P frags exchanged
    uint4 po = *(const uint4*)(pb + (wid ^ 2) * 1024 + lane * 16);
    long own0 = __builtin_bit_cast(long, uintx2{G0, G1});
    long own1 = __builtin_bit_cast(long, uintx2{G2, G3});
    long pr0 = __builtin_bit_cast(long, uintx2{po.x, po.y});
    long pr1 = __builtin_bit_cast(long, uintx2{po.z, po.w});
    long s0 = h ? pr0 : own0, s1 = h ? pr1 : own1;
    long s2 = h ? own0 : pr0, s3 = h ? own1 : pr1;
    __builtin_amdgcn_s_setprio(1);
#pragma unroll
    for (int ct = 0; ct < 4; ++ct) {
      longx2 vv = *(const longx2*)(bV + voff2[ct]);
      acc[ct] = __builtin_amdgcn_mfma_f32_32x32x16_fp8_fp8(s0, vv[0], acc[ct], 0, 0, 0);
      acc[ct] = __builtin_amdgcn_mfma_f32_32x32x16_fp8_fp8(s1, vv[1], acc[ct], 0, 0, 0);
    }
#pragma unroll
    for (int ct = 0; ct < 4; ++ct) {
      longx2 vv = *(const longx2*)(bV + voff2[4 + ct]);
      acc[ct] = __builtin_amdgcn_mfma_f32_32x32x16_fp8_fp8(s2, vv[0], acc[ct], 0, 0, 0);
      acc[ct] = __builtin_amdgcn_mfma_f32_32x32x16_fp8_fp8(s3, vv[1], acc[ct], 0, 0, 0);
    }
    __builtin_amdgcn_s_setprio(0);
    __builtin_amdgcn_s_barrier();  // C: tile + Pbuf reads done before restage
  }

  float ls = cross_half_sum(lsum);
  exls[wid * 64 + lane] = ls;
  __syncthreads();
  ls += exls[(wid ^ 2) * 64 + lane];
  float inv = 1.f / ls;
  float invR[16];
#pragma unroll
  for (int r = 0; r < 16; ++r)
    invR[r] = __shfl(inv, (r & 3) + 8 * (r >> 2) + 4 * hi);
  bf16_t* Ob = OT + (size_t)b * (kN * kC);
#pragma unroll
  for (int ct = 0; ct < 4; ++ct)
#pragma unroll
    for (int r = 0; r < 16; ++r) {
      int qr = (r & 3) + 8 * (r >> 2) + 4 * hi;
      Ob[(size_t)(q0 + qr) * kC + h * 128 + ct * 32 + l31] =
          (bf16_t)(acc[ct][r] * invR[r]);
    }
}

// ---- merged QKV GEMM v2: HN-resident panel. grid = B x 8 token-panels, 512 thr ----
// Block stages its 64KB HN panel ONCE; loops tmi=0..5 (W tiles dbuf'd, L2-hot).
// 8 waves = 4(wm) x 2(wn); wave owns 32 rows x 64 cols; acc[2][4].
// Epilogue per tmi: tmi 0-1 -> Q_t fp8 hi-major, 2-3 -> K_t, 4-5 -> V fp8 packed.
__global__ __launch_bounds__(512) void qkv_gemm_k(const bf16_t* __restrict__ W,
                                                  const bf16_t* __restrict__ HNall,
                                                  char* __restrict__ QTo,
                                                  char* __restrict__ KTo,
                                                  char* __restrict__ VVo,
                                                  const float* __restrict__ bq,
                                                  const float* __restrict__ bk,
                                                  const float* __restrict__ bv) {
  __shared__ bf16_t lH[128 * 256];     // HN panel [token][C], chunk slot ^= row&7
  __shared__ bf16_t lW[2][128 * 64];   // W tile dbuf
  int bid = blockIdx.x;
  int b = bid >> 3, tni = bid & 7;
  const bf16_t* Bb = HNall + (size_t)b * (kN * kC) + (size_t)tni * 128 * 256;
  int t = threadIdx.x;
  int wid = t >> 6, l = t & 63;
  int wm = wid >> 1, wn = wid & 1;
  int lr = l & 15, lk = l >> 4;
  // staging offsets (pre-swizzled global sources, rule 21)
  unsigned hoff[8];
#pragma unroll
  for (int i = 0; i < 8; ++i) {
    int d = i * 512 + t;           // dest chunk: row = d>>5, slot = d&31
    int row = d >> 5, sp = d & 31;
    hoff[i] = row * 256 + ((sp ^ (row & 7)) << 3);
  }
  unsigned woff[2];
#pragma unroll
  for (int i = 0; i < 2; ++i) {
    int d = i * 512 + t;           // dest chunk: row = d>>3, slot = d&7
    int row = d >> 3, sp = d & 7;
    woff[i] = row * 256 + ((sp ^ (row & 7)) << 3);
  }
  // fragment read offsets
  unsigned aoff[2][8];  // [mf][kk*4? ] -> A from W tile [128][64]
#pragma unroll
  for (int kk = 0; kk < 2; ++kk)
#pragma unroll
    for (int mf = 0; mf < 2; ++mf) {
      int ra = wm * 32 + mf * 16 + lr;
      int ch = kk * 4 + lk;
      aoff[mf][kk] = ra * 64 + ((ch ^ (ra & 7)) << 3);
    }
  unsigned bofs[4];  // B rows (tokens) per nf; chunk added at use
#pragma unroll
  for (int nf = 0; nf < 4; ++nf) bofs[nf] = (unsigned)(wn * 64 + nf * 16 + lr);

  // prologue: HN panel (8 loads) + W(tmi=0, ks=0) (2 loads)
#pragma unroll
  for (int i = 0; i < 8; ++i)
    gload_lds16(Bb + hoff[i], lH + (size_t)(i * 512 + t) * 8);
  const bf16_t* Wb = W;
#pragma unroll
  for (int i = 0; i < 2; ++i)
    gload_lds16(Wb + woff[i], &lW[0][(i * 512 + t) * 8]);

  f32x4 acc[2][4] = {};
  for (int st = 0; st < 24; ++st) {  // st = tmi*4 + ks
    int tmi = st >> 2, ks = st & 3;
    if (st < 23) {
      int nst = st + 1;
      const bf16_t* Wn = W + (size_t)(nst >> 2) * 128 * 256 + (nst & 3) * 64;
#pragma unroll
      for (int i = 0; i < 2; ++i)
        gload_lds16(Wn + woff[i], &lW[nst & 1][(i * 512 + t) * 8]);
      asm volatile("s_waitcnt vmcnt(2)" ::: "memory");
    } else {
      asm volatile("s_waitcnt vmcnt(0)" ::: "memory");
    }
    __builtin_amdgcn_s_barrier();
    const bf16_t* cW = lW[st & 1];
#pragma unroll
    for (int kk = 0; kk < 2; ++kk) {
      bf16x8 af[2], bfr[4];
#pragma unroll
      for (int mf = 0; mf < 2; ++mf) af[mf] = *(const bf16x8*)(cW + aoff[mf][kk]);
      int chh = ks * 8 + kk * 4 + lk;  // chunk in 256-wide HN row
#pragma unroll
      for (int nf = 0; nf < 4; ++nf) {
        unsigned rb2 = bofs[nf];
        bfr[nf] = *(const bf16x8*)(lH + rb2 * 256 + ((chh ^ (rb2 & 7)) << 3));
      }
#pragma unroll
      for (int mf = 0; mf < 2; ++mf)
#pragma unroll
        for (int nf = 0; nf < 4; ++nf)
          acc[mf][nf] = __builtin_amdgcn_mfma_f32_16x16x32_bf16(af[mf], bfr[nf],
                                                                acc[mf][nf], 0, 0, 0);
    }
    if (ks == 3) {  // epilogue for this tmi, then reset acc
      int seg = tmi >> 1;
      int rbase = (tmi & 1) * 128 + wm * 32;
      int cb = tni * 128 + wn * 64;
      if (seg < 2) {
        char* D = (seg ? KTo : QTo) + (size_t)b * (kN * kC);
        const float* bias = seg ? bk : bq;
#pragma unroll
        for (int mf = 0; mf < 2; ++mf)
#pragma unroll
          for (int nf = 0; nf < 4; ++nf) {
            int r0 = rbase + mf * 16 + lk * 4;
            int c = cb + nf * 16 + lr;
            unsigned u = pk_fp8x4(acc[mf][nf][0] + bias[r0], acc[mf][nf][1] + bias[r0 + 1],
                                  acc[mf][nf][2] + bias[r0 + 2], acc[mf][nf][3] + bias[r0 + 3]);
            int np = ((r0 >> 3) & 1) * 128 + (r0 >> 4) * 8 + (r0 & 7);  // hi-major remap
            *(unsigned*)(D + (size_t)c * kC + np) = u;
          }
      } else {
        char* D = VVo + (size_t)b * (kC * kN);
#pragma unroll
        for (int mf = 0; mf < 2; ++mf)
#pragma unroll
          for (int nf = 0; nf < 4; ++nf) {
            int r0 = rbase + mf * 16 + lk * 4;
            int c = cb + nf * 16 + lr;
            unsigned u = pk_fp8x4(acc[mf][nf][0] + bv[r0], acc[mf][nf][1] + bv[r0 + 1],
                                  acc[mf][nf][2] + bv[r0 + 2], acc[mf][nf][3] + bv[r0 + 3]);
            int kv = c & 63, tile = c >> 6;
            int sp = kv >> 5;
            int base = tile * 64 + ((kv >> 3) & 1) * 16 + ((kv >> 4) & 1) * 8 + (kv & 7);
#pragma unroll
            for (int i = 0; i < 4; ++i) {
              int ch = r0 + i;
              int pos = base + ((sp ^ ((ch >> 1) & 1)) << 5);
              D[(size_t)ch * kN + pos] = (char)(u >> (8 * i));
            }
          }
      }
#pragma unroll
      for (int mf = 0; mf < 2; ++mf)
#pragma unroll
        for (int nf = 0; nf < 4; ++nf) acc[mf][nf] = f32x4{0.f, 0.f, 0.f, 0.f};
    }
    __builtin_amdgcn_s_barrier();  // W-buffer reads done before restage
  }
}

// ---------- out-proj GEMM (R9 proven), dbuf stage-ahead + hoisted offsets ----------
__global__ __launch_bounds__(256) void out_gemm_k(const bf16_t* __restrict__ A,  // O_t
                                                  const bf16_t* __restrict__ BT, // Wh
                                                  float* __restrict__ Dst,
                                                  const float* __restrict__ bias,
                                                  const float* __restrict__ resid) {
  __shared__ bf16_t lA[2][128 * 64];
  __shared__ bf16_t lB[2][128 * 64];
  int bid = blockIdx.x;
  int b = bid >> 4;
  int rem = bid & 15;
  int tmi = rem >> 1, tni = rem & 1;
  const bf16_t* Ab = A + (size_t)b * (kN * kC) + (size_t)tmi * 128 * 256;
  const bf16_t* Bb = BT + (size_t)tni * 128 * 256;
  int t = threadIdx.x;
  int wid = t >> 6, l = t & 63;
  int wm = wid >> 1, wn = wid & 1;
  int lr = l & 15, lk = l >> 4;
  unsigned goff[4];
#pragma unroll
  for (int i = 0; i < 4; ++i) {
    int ci = i * 256 + t;
    int row = ci >> 3, s = ci & 7;
    goff[i] = row * 256 + ((s ^ (row & 7)) << 3);
  }
  unsigned aoff[8], boff[8];
#pragma unroll
  for (int kk = 0; kk < 2; ++kk)
#pragma unroll
    for (int f = 0; f < 4; ++f) {
      int ra = wm * 64 + f * 16 + lr;
      int rb2 = wn * 64 + f * 16 + lr;
      int ch = kk * 4 + lk;
      aoff[kk * 4 + f] = ra * 64 + ((ch ^ (ra & 7)) << 3);
      boff[kk * 4 + f] = rb2 * 64 + ((ch ^ (rb2 & 7)) << 3);
    }
  f32x4 acc[4][4] = {};
  auto STAGE = [&](int buf, int k0) {
#pragma unroll
    for (int i = 0; i < 4; ++i) {
      gload_lds16(Ab + k0 + goff[i], &lA[buf][t * 8 + i * 2048]);
      gload_lds16(Bb + k0 + goff[i], &lB[buf][t * 8 + i * 2048]);
    }
  };
  STAGE(0, 0);
  for (int kt = 0; kt < 4; ++kt) {
    if (kt < 3) {
      STAGE((kt + 1) & 1, (kt + 1) * 64);
      asm volatile("s_waitcnt vmcnt(8)" ::: "memory");
    } else {
      asm volatile("s_waitcnt vmcnt(0)" ::: "memory");
    }
    __builtin_amdgcn_s_barrier();
    const bf16_t* cA = lA[kt & 1];
    const bf16_t* cB = lB[kt & 1];
#pragma unroll
    for (int kk = 0; kk < 2; ++kk) {
      bf16x8 af[4], bfr[4];
#pragma unroll
      for (int f = 0; f < 4; ++f) {
        af[f] = *(const bf16x8*)(cA + aoff[kk * 4 + f]);
        bfr[f] = *(const bf16x8*)(cB + boff[kk * 4 + f]);
      }
#pragma unroll
      for (int mf = 0; mf < 4; ++mf)
#pragma unroll
        for (int nf = 0; nf < 4; ++nf)
          acc[mf][nf] = __builtin_amdgcn_mfma_f32_16x16x32_bf16(af[mf], bfr[nf],
                                                                acc[mf][nf], 0, 0, 0);
    }
    __builtin_amdgcn_s_barrier();
  }
  int rb = tmi * 128 + wm * 64;
  int cb = tni * 128 + wn * 64;
  float* D = Dst + (size_t)b * (kC * kN);
  const float* R = resid + (size_t)b * (kC * kN);
#pragma unroll
  for (int mf = 0; mf < 4; ++mf)
#pragma unroll
    for (int nf = 0; nf < 4; ++nf) {
      int r0 = rb + mf * 16 + lk * 4;  // token n
      int c = cb + nf * 16 + lr;       // channel co
      float4 rv = *(const float4*)(R + (size_t)c * kN + r0);
      float bc = bias[c];
      float4 o2 = make_float4(acc[mf][nf][0] + rv.x + bc, acc[mf][nf][1] + rv.y + bc,
                              acc[mf][nf][2] + rv.z + bc, acc[mf][nf][3] + rv.w + bc);
      *(float4*)(D + (size_t)c * kN + r0) = o2;
    }
}

extern "C" void kernel_launch(void* const* d_in, const int* in_sizes, int n_in,
                              void* d_out, int out_size, void* d_ws, size_t ws_size,
                              hipStream_t stream) {
  (void)in_sizes; (void)n_in; (void)out_size; (void)ws_size;
  const float* x = (const float*)d_in[0];
  const float* gamma = (const float*)d_in[1];
  const float* beta = (const float*)d_in[2];
  const float* wq = (const float*)d_in[3];
  const float* bq = (const float*)d_in[4];
  const float* wk = (const float*)d_in[5];
  const float* bk = (const float*)d_in[6];
  const float* wv = (const float*)d_in[7];
  const float* bv = (const float*)d_in[8];
  const float* wh = (const float*)d_in[9];
  const float* bh = (const float*)d_in[10];
  float* out = (float*)d_out;

  char* ws = (char*)d_ws;
  bf16_t* HN = (bf16_t*)(ws);             // Hn_t [B][N][C] bf16; reused as O_t after fattn
  char* QT = ws + 16777216;               // Q_t [B][N][C] fp8 hi-major rows
  char* KT = ws + 25165824;               // K_t [B][N][C] fp8 hi-major rows
  char* VV = ws + 33554432;               // V   [B][C][N] fp8 slot-pair packed
  bf16_t* WB = (bf16_t*)(ws + 50331648);  // Wq|Wk|Wv|Wh bf16 (stacked)

  gn_castw_k<<<kB * 32 + 256, 256, 0, stream>>>(x, gamma, beta, HN, wq, wk, wv, wh, WB);
  qkv_gemm_k<<<kB * 8, 512, 0, stream>>>(WB, HN, QT, KT, VV, bq, bk, bv);
  fattn_k<<<512, 256, 0, stream>>>(QT, KT, VV, HN);
  out_gemm_k<<<kB * 16, 256, 0, stream>>>(HN, WB + 196608, out, bh, x);
}

// Round 18
// 102.190 us; speedup vs baseline: 1.0839x; 1.0839x over previous
//
#include <hip/hip_runtime.h>

typedef __bf16 bf16_t;
typedef __bf16 bf16x8 __attribute__((ext_vector_type(8)));
typedef __bf16 bf16x4 __attribute__((ext_vector_type(4)));
typedef float f32x4 __attribute__((ext_vector_type(4)));
typedef float f32x16 __attribute__((ext_vector_type(16)));
typedef long longx2 __attribute__((ext_vector_type(2)));
typedef unsigned uintx2 __attribute__((ext_vector_type(2)));

static constexpr int kC = 256;   // channels
static constexpr int kN = 1024;  // tokens (32x32)
static constexpr int kB = 32;    // batch

__device__ __forceinline__ void gload_lds16(const void* g, void* l) {
  __builtin_amdgcn_global_load_lds(
      (const __attribute__((address_space(1))) unsigned int*)g,
      (__attribute__((address_space(3))) unsigned int*)l, 16, 0, 0);
}

// pack 4 f32 -> 4 fp8 e4m3 bytes (lo word then hi word)
__device__ __forceinline__ unsigned pk_fp8x4(float a, float b, float c, float d) {
  unsigned r;
  asm("v_cvt_pk_fp8_f32 %0, %1, %2" : "=v"(r) : "v"(a), "v"(b));
  asm("v_cvt_pk_fp8_f32 %0, %1, %2 op_sel:[0,0,1]" : "+v"(r) : "v"(c), "v"(d));
  return r;
}

// exchange: a's high 32 lanes <-> b's low 32 lanes (both regs updated)
__device__ __forceinline__ void pl32swap(unsigned& a, unsigned& b) {
  asm("v_permlane32_swap_b32 %0, %1" : "+v"(a), "+v"(b));
}

__device__ __forceinline__ float cross_half_sum(float rs) {
  unsigned a = __builtin_bit_cast(unsigned, rs), b = a;
  pl32swap(a, b);
  return __builtin_bit_cast(float, a) + __builtin_bit_cast(float, b);
}

// ------- fused GroupNorm (+ weight cast blocks): grid = 1024 gn + 256 castw -------
__global__ __launch_bounds__(256) void gn_castw_k(const float* __restrict__ x,
                                                  const float* __restrict__ gamma,
                                                  const float* __restrict__ beta,
                                                  bf16_t* __restrict__ hn,
                                                  const float* __restrict__ wq,
                                                  const float* __restrict__ wk,
                                                  const float* __restrict__ wv,
                                                  const float* __restrict__ wh,
                                                  bf16_t* __restrict__ wb) {
  __shared__ float xs[8 * 1040];  // [c_local][n] pad 1040
  __shared__ float red[8];
  __shared__ float stat[2];
  int t = threadIdx.x;
  if (blockIdx.x >= 1024) {  // weight cast: 256 blocks x 256 thr
    int i = (blockIdx.x - 1024) * 256 + t;
    wb[i] = (bf16_t)wq[i];
    wb[i + 65536] = (bf16_t)wk[i];
    wb[i + 131072] = (bf16_t)wv[i];
    wb[i + 196608] = (bf16_t)wh[i];
    return;
  }
  int bg = blockIdx.x;
  int b = bg >> 5, g = bg & 31;
  const float* base = x + (size_t)bg * 8192;
  float s = 0.f, q = 0.f;
#pragma unroll
  for (int i = 0; i < 8; ++i) {
    float4 v = *(const float4*)(base + i * 1024 + t * 4);
    *(float4*)(xs + i * 1040 + t * 4) = v;
    s += v.x + v.y + v.z + v.w;
    q += v.x * v.x + v.y * v.y + v.z * v.z + v.w * v.w;
  }
#pragma unroll
  for (int o = 32; o; o >>= 1) { s += __shfl_down(s, o); q += __shfl_down(q, o); }
  int w = t >> 6;
  if ((t & 63) == 0) { red[w] = s; red[4 + w] = q; }
  __syncthreads();
  if (t == 0) {
    float S = red[0] + red[1] + red[2] + red[3];
    float Q = red[4] + red[5] + red[6] + red[7];
    float mean = S * (1.f / 8192.f);
    float var = Q * (1.f / 8192.f) - mean * mean;  // biased var matches jnp.var
    stat[0] = mean;
    stat[1] = rsqrtf(var + 1e-5f);
  }
  __syncthreads();
  float mean = stat[0], rstd = stat[1];
  float gmb[8], btb[8];
#pragma unroll
  for (int j = 0; j < 8; ++j) { gmb[j] = gamma[g * 8 + j]; btb[j] = beta[g * 8 + j]; }
  bf16_t* hb = hn + (size_t)b * (kN * kC) + g * 8;
#pragma unroll
  for (int i = 0; i < 4; ++i) {
    int n = i * 256 + t;
    bf16x8 o;
#pragma unroll
    for (int j = 0; j < 8; ++j)
      o[j] = (bf16_t)((xs[j * 1040 + n] - mean) * rstd * gmb[j] + btb[j]);
    *(bf16x8*)(hb + (size_t)n * kC) = o;
  }
}

// ---- fused flash attention (R16 winner): non-redundant QK, fp8 P/V, KVBLK=64 ----
__global__ __launch_bounds__(256, 2) void fattn_k(const char* __restrict__ QT,
                                                  const char* __restrict__ KT,
                                                  const char* __restrict__ VV,
                                                  bf16_t* __restrict__ OT) {
  __shared__ char smem[70656];  // K[2][16K] | V[2][16K]@32768 | P 4K@65536 | ex 1K@69632
  char* lKc = smem;
  char* lVc = smem + 32768;
  char* pb = smem + 65536;
  float* exls = (float*)(smem + 69632);
  int t = threadIdx.x;
  int wid = t >> 6, lane = t & 63;
  int l31 = lane & 31, hi = lane >> 5;
  int qg = wid & 1, h = wid >> 1;
  int bid = blockIdx.x;
  int b = ((bid & 7) << 2) | ((bid >> 3) & 3);  // XCD swizzle
  int qt = bid >> 5;
  const char* Qb = QT + (size_t)b * (kN * kC);
  int q0 = qt * 64 + qg * 32;
  constexpr float kSc = 0.0625f * 1.44269504f;  // (1/sqrt C) * log2(e)

  long qf[16];
#pragma unroll
  for (int jj = 0; jj < 8; ++jj) {
    longx2 qp = *(const longx2*)(Qb + (size_t)(q0 + l31) * kC + hi * 128 + jj * 16);
    qf[2 * jj] = qp[0];
    qf[2 * jj + 1] = qp[1];
  }

  unsigned koff2[8];
#pragma unroll
  for (int jj = 0; jj < 8; ++jj)
    koff2[jj] = (h * 32 + l31) * 256 + (((hi * 8 + jj) ^ (l31 & 15)) << 4);
  unsigned voff2[8];
#pragma unroll
  for (int sp = 0; sp < 2; ++sp)
#pragma unroll
    for (int ct = 0; ct < 4; ++ct) {
      int c = h * 128 + ct * 32 + l31;
      voff2[sp * 4 + ct] = c * 64 + ((sp ^ ((c >> 1) & 1)) << 5) + hi * 16;
    }

  unsigned koffg[4], voffg[4];
#pragma unroll
  for (int i = 0; i < 4; ++i) {
    int ck = i * 256 + t;
    int row = ck >> 4, s = ck & 15;
    koffg[i] = row * 256 + ((s ^ (row & 15)) << 4);
    int cv = i * 256 + t;
    voffg[i] = (cv >> 2) * 1024 + ((cv & 3) << 4);
  }
  const char* kSrc = KT + (size_t)b * (kN * kC);
  const char* vSrc = VV + (size_t)b * (kC * kN);
  char* kd0 = lKc + t * 16;
  char* vd0 = lVc + t * 16;

  f32x16 acc[4] = {};
  float lsum = 0.f;

  auto STAGE = [&](int buf) {
#pragma unroll
    for (int i = 0; i < 4; ++i)
      gload_lds16(kSrc + koffg[i], kd0 + buf * 16384 + i * 4096);
#pragma unroll
    for (int i = 0; i < 4; ++i)
      gload_lds16(vSrc + voffg[i], vd0 + buf * 16384 + i * 4096);
    kSrc += 16384;
    vSrc += 64;
  };

  STAGE(0);
  for (int kt = 0; kt < 16; ++kt) {
    if (kt < 15) {
      STAGE((kt + 1) & 1);
      asm volatile("s_waitcnt vmcnt(8)" ::: "memory");
    } else {
      asm volatile("s_waitcnt vmcnt(0)" ::: "memory");
    }
    __builtin_amdgcn_s_barrier();  // A: tile staged; prev P fully consumed
    const char* bK = lKc + (kt & 1) * 16384;
    const char* bV = lVc + (kt & 1) * 16384;
    f32x16 sa = {};
    __builtin_amdgcn_s_setprio(1);
#pragma unroll
    for (int jj = 0; jj < 8; ++jj) {
      longx2 ka = *(const longx2*)(bK + koff2[jj]);
      sa = __builtin_amdgcn_mfma_f32_32x32x16_fp8_fp8(ka[0], qf[2 * jj], sa, 0, 0, 0);
      sa = __builtin_amdgcn_mfma_f32_32x32x16_fp8_fp8(ka[1], qf[2 * jj + 1], sa, 0, 0, 0);
    }
    __builtin_amdgcn_s_setprio(0);
    float rs = 0.f;
    float e0 = exp2f(sa[0] * kSc), e1 = exp2f(sa[1] * kSc);
    float e2 = exp2f(sa[2] * kSc), e3 = exp2f(sa[3] * kSc);
    float e4 = exp2f(sa[4] * kSc), e5 = exp2f(sa[5] * kSc);
    float e6 = exp2f(sa[6] * kSc), e7 = exp2f(sa[7] * kSc);
    rs += e0 + e1 + e2 + e3 + e4 + e5 + e6 + e7;
    unsigned G0 = pk_fp8x4(e0, e1, e2, e3), G1 = pk_fp8x4(e4, e5, e6, e7);
    pl32swap(G0, G1);
    e0 = exp2f(sa[8] * kSc);  e1 = exp2f(sa[9] * kSc);
    e2 = exp2f(sa[10] * kSc); e3 = exp2f(sa[11] * kSc);
    e4 = exp2f(sa[12] * kSc); e5 = exp2f(sa[13] * kSc);
    e6 = exp2f(sa[14] * kSc); e7 = exp2f(sa[15] * kSc);
    rs += e0 + e1 + e2 + e3 + e4 + e5 + e6 + e7;
    lsum += rs;
    unsigned G2 = pk_fp8x4(e0, e1, e2, e3), G3 = pk_fp8x4(e4, e5, e6, e7);
    pl32swap(G2, G3);
    *(uint4*)(pb + wid * 1024 + lane * 16) = make_uint4(G0, G1, G2, G3);
    asm volatile("s_waitcnt lgkmcnt(0)" ::: "memory");
    __builtin_amdgcn_s_barrier();  // B: P frags exchanged
    uint4 po = *(const uint4*)(pb + (wid ^ 2) * 1024 + lane * 16);
    long own0 = __builtin_bit_cast(long, uintx2{G0, G1});
    long own1 = __builtin_bit_cast(long, uintx2{G2, G3});
    long pr0 = __builtin_bit_cast(long, uintx2{po.x, po.y});
    long pr1 = __builtin_bit_cast(long, uintx2{po.z, po.w});
    long s0 = h ? pr0 : own0, s1 = h ? pr1 : own1;
    long s2 = h ? own0 : pr0, s3 = h ? own1 : pr1;
    __builtin_amdgcn_s_setprio(1);
#pragma unroll
    for (int ct = 0; ct < 4; ++ct) {
      longx2 vv = *(const longx2*)(bV + voff2[ct]);
      acc[ct] = __builtin_amdgcn_mfma_f32_32x32x16_fp8_fp8(s0, vv[0], acc[ct], 0, 0, 0);
      acc[ct] = __builtin_amdgcn_mfma_f32_32x32x16_fp8_fp8(s1, vv[1], acc[ct], 0, 0, 0);
    }
#pragma unroll
    for (int ct = 0; ct < 4; ++ct) {
      longx2 vv = *(const longx2*)(bV + voff2[4 + ct]);
      acc[ct] = __builtin_amdgcn_mfma_f32_32x32x16_fp8_fp8(s2, vv[0], acc[ct], 0, 0, 0);
      acc[ct] = __builtin_amdgcn_mfma_f32_32x32x16_fp8_fp8(s3, vv[1], acc[ct], 0, 0, 0);
    }
    __builtin_amdgcn_s_setprio(0);
    __builtin_amdgcn_s_barrier();  // C: tile + Pbuf reads done before restage
  }

  float ls = cross_half_sum(lsum);
  exls[wid * 64 + lane] = ls;
  __syncthreads();
  ls += exls[(wid ^ 2) * 64 + lane];
  float inv = 1.f / ls;
  float invR[16];
#pragma unroll
  for (int r = 0; r < 16; ++r)
    invR[r] = __shfl(inv, (r & 3) + 8 * (r >> 2) + 4 * hi);
  bf16_t* Ob = OT + (size_t)b * (kN * kC);
#pragma unroll
  for (int ct = 0; ct < 4; ++ct)
#pragma unroll
    for (int r = 0; r < 16; ++r) {
      int qr = (r & 3) + 8 * (r >> 2) + 4 * hi;
      Ob[(size_t)(q0 + qr) * kC + h * 128 + ct * 32 + l31] =
          (bf16_t)(acc[ct][r] * invR[r]);
    }
}

// ------- merged QKV GEMM (R16 proven): Q/K fp8 hi-major rows, V fp8 packed -------
// W stacked [768][256]; tmi 0-1 -> Q_t, 2-3 -> K_t, 4-5 -> V packed [c][1024B]
__global__ __launch_bounds__(256) void qkv_gemm_k(const bf16_t* __restrict__ W,
                                                  const bf16_t* __restrict__ HNall,
                                                  char* __restrict__ QTo,
                                                  char* __restrict__ KTo,
                                                  char* __restrict__ VVo,
                                                  const float* __restrict__ bq,
                                                  const float* __restrict__ bk,
                                                  const float* __restrict__ bv) {
  __shared__ bf16_t lA[2][128 * 64];
  __shared__ bf16_t lB[2][128 * 64];
  int bid = blockIdx.x;
  int b = bid / 48;
  int rem = bid - b * 48;
  int tmi = rem >> 3, tni = rem & 7;
  const bf16_t* Ab = W + (size_t)tmi * 128 * 256;
  const bf16_t* Bb = HNall + (size_t)b * (kN * kC) + (size_t)tni * 128 * 256;
  int t = threadIdx.x;
  int wid = t >> 6, l = t & 63;
  int wm = wid >> 1, wn = wid & 1;
  int lr = l & 15, lk = l >> 4;
  unsigned goff[4];
#pragma unroll
  for (int i = 0; i < 4; ++i) {
    int ci = i * 256 + t;
    int row = ci >> 3, s = ci & 7;
    goff[i] = row * 256 + ((s ^ (row & 7)) << 3);
  }
  unsigned aoff[8], boff[8];
#pragma unroll
  for (int kk = 0; kk < 2; ++kk)
#pragma unroll
    for (int f = 0; f < 4; ++f) {
      int ra = wm * 64 + f * 16 + lr;
      int rb2 = wn * 64 + f * 16 + lr;
      int ch = kk * 4 + lk;
      aoff[kk * 4 + f] = ra * 64 + ((ch ^ (ra & 7)) << 3);
      boff[kk * 4 + f] = rb2 * 64 + ((ch ^ (rb2 & 7)) << 3);
    }
  f32x4 acc[4][4] = {};
  auto STAGE = [&](int buf, int k0) {
#pragma unroll
    for (int i = 0; i < 4; ++i) {
      gload_lds16(Ab + k0 + goff[i], &lA[buf][t * 8 + i * 2048]);
      gload_lds16(Bb + k0 + goff[i], &lB[buf][t * 8 + i * 2048]);
    }
  };
  STAGE(0, 0);
  for (int kt = 0; kt < 4; ++kt) {
    if (kt < 3) {
      STAGE((kt + 1) & 1, (kt + 1) * 64);
      asm volatile("s_waitcnt vmcnt(8)" ::: "memory");
    } else {
      asm volatile("s_waitcnt vmcnt(0)" ::: "memory");
    }
    __builtin_amdgcn_s_barrier();
    const bf16_t* cA = lA[kt & 1];
    const bf16_t* cB = lB[kt & 1];
#pragma unroll
    for (int kk = 0; kk < 2; ++kk) {
      bf16x8 af[4], bfr[4];
#pragma unroll
      for (int f = 0; f < 4; ++f) {
        af[f] = *(const bf16x8*)(cA + aoff[kk * 4 + f]);
        bfr[f] = *(const bf16x8*)(cB + boff[kk * 4 + f]);
      }
#pragma unroll
      for (int mf = 0; mf < 4; ++mf)
#pragma unroll
        for (int nf = 0; nf < 4; ++nf)
          acc[mf][nf] = __builtin_amdgcn_mfma_f32_16x16x32_bf16(af[mf], bfr[nf],
                                                                acc[mf][nf], 0, 0, 0);
    }
    __builtin_amdgcn_s_barrier();
  }
  int seg = tmi >> 1;
  int rb = (tmi & 1) * 128 + wm * 64;
  int cb = tni * 128 + wn * 64;
  if (seg < 2) {  // Q_t / K_t: fp8 store at hi-major position + bias[r]
    char* D = (seg ? KTo : QTo) + (size_t)b * (kN * kC);
    const float* bias = seg ? bk : bq;
#pragma unroll
    for (int mf = 0; mf < 4; ++mf)
#pragma unroll
      for (int nf = 0; nf < 4; ++nf) {
        int r0 = rb + mf * 16 + lk * 4;
        int c = cb + nf * 16 + lr;
        unsigned u = pk_fp8x4(acc[mf][nf][0] + bias[r0], acc[mf][nf][1] + bias[r0 + 1],
                              acc[mf][nf][2] + bias[r0 + 2], acc[mf][nf][3] + bias[r0 + 3]);
        int np = ((r0 >> 3) & 1) * 128 + (r0 >> 4) * 8 + (r0 & 7);  // hi-major remap
        *(unsigned*)(D + (size_t)c * kC + np) = u;
      }
  } else {  // V: fp8 packed store; rows r0..r0+3 = channels, c = token
    char* D = VVo + (size_t)b * (kC * kN);
#pragma unroll
    for (int mf = 0; mf < 4; ++mf)
#pragma unroll
      for (int nf = 0; nf < 4; ++nf) {
        int r0 = rb + mf * 16 + lk * 4;
        int c = cb + nf * 16 + lr;
        unsigned u = pk_fp8x4(acc[mf][nf][0] + bv[r0], acc[mf][nf][1] + bv[r0 + 1],
                              acc[mf][nf][2] + bv[r0 + 2], acc[mf][nf][3] + bv[r0 + 3]);
        int kv = c & 63, tile = c >> 6;
        int sp = kv >> 5;
        int base = tile * 64 + ((kv >> 3) & 1) * 16 + ((kv >> 4) & 1) * 8 + (kv & 7);
#pragma unroll
        for (int i = 0; i < 4; ++i) {
          int ch = r0 + i;
          int pos = base + ((sp ^ ((ch >> 1) & 1)) << 5);
          D[(size_t)ch * kN + pos] = (char)(u >> (8 * i));
        }
      }
  }
}

// ---------- out-proj GEMM (R9 proven), dbuf stage-ahead + hoisted offsets ----------
__global__ __launch_bounds__(256) void out_gemm_k(const bf16_t* __restrict__ A,  // O_t
                                                  const bf16_t* __restrict__ BT, // Wh
                                                  float* __restrict__ Dst,
                                                  const float* __restrict__ bias,
                                                  const float* __restrict__ resid) {
  __shared__ bf16_t lA[2][128 * 64];
  __shared__ bf16_t lB[2][128 * 64];
  int bid = blockIdx.x;
  int b = bid >> 4;
  int rem = bid & 15;
  int tmi = rem >> 1, tni = rem & 1;
  const bf16_t* Ab = A + (size_t)b * (kN * kC) + (size_t)tmi * 128 * 256;
  const bf16_t* Bb = BT + (size_t)tni * 128 * 256;
  int t = threadIdx.x;
  int wid = t >> 6, l = t & 63;
  int wm = wid >> 1, wn = wid & 1;
  int lr = l & 15, lk = l >> 4;
  unsigned goff[4];
#pragma unroll
  for (int i = 0; i < 4; ++i) {
    int ci = i * 256 + t;
    int row = ci >> 3, s = ci & 7;
    goff[i] = row * 256 + ((s ^ (row & 7)) << 3);
  }
  unsigned aoff[8], boff[8];
#pragma unroll
  for (int kk = 0; kk < 2; ++kk)
#pragma unroll
    for (int f = 0; f < 4; ++f) {
      int ra = wm * 64 + f * 16 + lr;
      int rb2 = wn * 64 + f * 16 + lr;
      int ch = kk * 4 + lk;
      aoff[kk * 4 + f] = ra * 64 + ((ch ^ (ra & 7)) << 3);
      boff[kk * 4 + f] = rb2 * 64 + ((ch ^ (rb2 & 7)) << 3);
    }
  f32x4 acc[4][4] = {};
  auto STAGE = [&](int buf, int k0) {
#pragma unroll
    for (int i = 0; i < 4; ++i) {
      gload_lds16(Ab + k0 + goff[i], &lA[buf][t * 8 + i * 2048]);
      gload_lds16(Bb + k0 + goff[i], &lB[buf][t * 8 + i * 2048]);
    }
  };
  STAGE(0, 0);
  for (int kt = 0; kt < 4; ++kt) {
    if (kt < 3) {
      STAGE((kt + 1) & 1, (kt + 1) * 64);
      asm volatile("s_waitcnt vmcnt(8)" ::: "memory");
    } else {
      asm volatile("s_waitcnt vmcnt(0)" ::: "memory");
    }
    __builtin_amdgcn_s_barrier();
    const bf16_t* cA = lA[kt & 1];
    const bf16_t* cB = lB[kt & 1];
#pragma unroll
    for (int kk = 0; kk < 2; ++kk) {
      bf16x8 af[4], bfr[4];
#pragma unroll
      for (int f = 0; f < 4; ++f) {
        af[f] = *(const bf16x8*)(cA + aoff[kk * 4 + f]);
        bfr[f] = *(const bf16x8*)(cB + boff[kk * 4 + f]);
      }
#pragma unroll
      for (int mf = 0; mf < 4; ++mf)
#pragma unroll
        for (int nf = 0; nf < 4; ++nf)
          acc[mf][nf] = __builtin_amdgcn_mfma_f32_16x16x32_bf16(af[mf], bfr[nf],
                                                                acc[mf][nf], 0, 0, 0);
    }
    __builtin_amdgcn_s_barrier();
  }
  int rb = tmi * 128 + wm * 64;
  int cb = tni * 128 + wn * 64;
  float* D = Dst + (size_t)b * (kC * kN);
  const float* R = resid + (size_t)b * (kC * kN);
#pragma unroll
  for (int mf = 0; mf < 4; ++mf)
#pragma unroll
    for (int nf = 0; nf < 4; ++nf) {
      int r0 = rb + mf * 16 + lk * 4;  // token n
      int c = cb + nf * 16 + lr;       // channel co
      float4 rv = *(const float4*)(R + (size_t)c * kN + r0);
      float bc = bias[c];
      float4 o2 = make_float4(acc[mf][nf][0] + rv.x + bc, acc[mf][nf][1] + rv.y + bc,
                              acc[mf][nf][2] + rv.z + bc, acc[mf][nf][3] + rv.w + bc);
      *(float4*)(D + (size_t)c * kN + r0) = o2;
    }
}

extern "C" void kernel_launch(void* const* d_in, const int* in_sizes, int n_in,
                              void* d_out, int out_size, void* d_ws, size_t ws_size,
                              hipStream_t stream) {
  (void)in_sizes; (void)n_in; (void)out_size; (void)ws_size;
  const float* x = (const float*)d_in[0];
  const float* gamma = (const float*)d_in[1];
  const float* beta = (const float*)d_in[2];
  const float* wq = (const float*)d_in[3];
  const float* bq = (const float*)d_in[4];
  const float* wk = (const float*)d_in[5];
  const float* bk = (const float*)d_in[6];
  const float* wv = (const float*)d_in[7];
  const float* bv = (const float*)d_in[8];
  const float* wh = (const float*)d_in[9];
  const float* bh = (const float*)d_in[10];
  float* out = (float*)d_out;

  char* ws = (char*)d_ws;
  bf16_t* HN = (bf16_t*)(ws);             // Hn_t [B][N][C] bf16; reused as O_t after fattn
  char* QT = ws + 16777216;               // Q_t [B][N][C] fp8 hi-major rows
  char* KT = ws + 25165824;               // K_t [B][N][C] fp8 hi-major rows
  char* VV = ws + 33554432;               // V   [B][C][N] fp8 slot-pair packed
  bf16_t* WB = (bf16_t*)(ws + 50331648);  // Wq|Wk|Wv|Wh bf16 (stacked)

  gn_castw_k<<<kB * 32 + 256, 256, 0, stream>>>(x, gamma, beta, HN, wq, wk, wv, wh, WB);
  qkv_gemm_k<<<kB * 48, 256, 0, stream>>>(WB, HN, QT, KT, VV, bq, bk, bv);
  fattn_k<<<512, 256, 0, stream>>>(QT, KT, VV, HN);
  out_gemm_k<<<kB * 16, 256, 0, stream>>>(HN, WB + 196608, out, bh, x);
}